// Round 2
// baseline (1294.679 us; speedup 1.0000x reference)
//
#include <hip/hip_runtime.h>
#include <math.h>

#define KF 4752          // feature dim: 96 + 96 + 4560
#define G4 384           // 4*C1 gates
#define NPAIR 4560
#define EPSBN 1e-5f

// Segment geometry for T=300, N_SEG=50 (derived exactly, incl. banker's
// rounding of linspace at i=25: 150.5 -> 150).
__device__ __forceinline__ int seg_start(int s){ return (s<=24)? 6*s : 149 + 6*(s-25); }
__device__ __forceinline__ int seg_len(int s){ return (s==24)?5:6; }

// ---------------- precompute: Geff[m][o][v][c*25+u], Beff[m][o][v], pairs ----
__global__ void kGeff(const float* bn_g, const float* bn_v,
                      const float* Ap, const float* Ar, const float* Wg,
                      const float* bn2_g, const float* bn2_v, float* geff){
  int idx = blockIdx.x*256 + threadIdx.x;
  if (idx >= 2*96*25*75) return;
  int cu = idx % 75; int rest = idx/75;
  int v = rest % 25; rest /= 25;
  int o = rest % 96; int m = rest / 96;
  int c = cu/25, u = cu%25;
  int ch = (m*25+u)*3 + c;
  float s1 = bn_g[ch] / sqrtf(bn_v[ch] + EPSBN);
  float s2 = bn2_g[o] / sqrtf(bn2_v[o] + EPSBN);
  float acc = 0.f;
  for (int k=0;k<13;k++){
    float a = Ap[(k*25+v)*25+u] + Ar[(k*25+v)*25+u];
    acc += Wg[o*39 + k*3 + c] * a;
  }
  geff[idx] = acc * s1 * s2;
}

__global__ void kBeff(const float* bn_g,const float* bn_b,const float* bn_m,const float* bn_v,
                      const float* Ap,const float* Ar,const float* Wg,const float* bg,
                      const float* bn2_g,const float* bn2_b,const float* bn2_m,const float* bn2_v,
                      float* beff){
  int idx = blockIdx.x*256+threadIdx.x;
  if (idx >= 2*96*25) return;
  int v = idx%25; int rest = idx/25; int o = rest%96; int m = rest/96;
  float acc = 0.f;
  for (int k=0;k<13;k++) for(int c=0;c<3;c++){
    float w = Wg[o*39+k*3+c];
    for (int u=0;u<25;u++){
      int ch = (m*25+u)*3+c;
      float s1 = bn_g[ch]/sqrtf(bn_v[ch]+EPSBN);
      float t1 = bn_b[ch] - bn_m[ch]*s1;
      acc += w * (Ap[(k*25+v)*25+u]+Ar[(k*25+v)*25+u]) * t1;
    }
  }
  acc += bg[o];
  float s2 = bn2_g[o]/sqrtf(bn2_v[o]+EPSBN);
  beff[idx] = s2*(acc - bn2_m[o]) + bn2_b[o];
}

__global__ void kPairs(int* pairs){
  int k = blockIdx.x*256+threadIdx.x;
  if (k >= NPAIR) return;
  int i=0, rem=k;
  while (rem >= 95 - i){ rem -= (95 - i); i++; }
  int j = i + 1 + rem;
  pairs[k] = (i<<7) | j;
}

// ---------------- p[b=nm*25+v][t][o] = relu(sum_cu Geff*x + Beff) -----------
#define TTILE 10
__global__ __launch_bounds__(256) void kP(const float* x, const float* geff, const float* beff, float* p){
  int nm = blockIdx.y;            // 0..7  (n*2+m)
  int t0 = blockIdx.x * TTILE;
  int m  = nm % 2;
  __shared__ float xs[75*TTILE];
  int tid = threadIdx.x;
  for (int li = tid; li < 75*TTILE; li += 256){
    int u = li % 25; int rest = li/25; int tt = rest % TTILE; int c = rest / TTILE;
    xs[(c*25+u)*TTILE + tt] = x[(((size_t)nm*3 + c)*300 + (t0+tt))*25 + u];
  }
  __syncthreads();
  for (int ow = tid; ow < 2400; ow += 256){
    int o = ow % 96, v = ow / 96;
    const float* g = geff + ((size_t)(m*96+o)*25 + v)*75;
    float b = beff[(m*96+o)*25+v];
    float acc[TTILE];
    #pragma unroll
    for (int t=0;t<TTILE;t++) acc[t] = b;
    for (int cu=0; cu<75; cu++){
      float gv = g[cu];
      #pragma unroll
      for (int t=0;t<TTILE;t++) acc[t] += gv * xs[cu*TTILE+t];
    }
    #pragma unroll
    for (int t=0;t<TTILE;t++)
      p[((size_t)(nm*25+v)*300 + t0+t)*96 + o] = fmaxf(acc[t], 0.f);
  }
}

// ---------------- feat rows: [start(96) | s1(96) | ls2(4560)] ---------------
__global__ __launch_bounds__(256) void kFeat(const float* p, const int* pairs, float* feat, int row0){
  int row = row0 + blockIdx.x;
  int b = row / 50, s = row % 50;
  int S = seg_start(s), len = seg_len(s);
  __shared__ float ps[6][96];
  __shared__ float ds[6][96];
  int tid = threadIdx.x;
  float* frow = feat + (size_t)blockIdx.x * KF;
  if (tid < 96){
    int c = tid;
    float pv[7];
    #pragma unroll
    for (int l=0;l<7;l++) pv[l] = p[((size_t)b*300 + S + l)*96 + c];
    float run = 0.f;
    #pragma unroll
    for (int l=0;l<6;l++){
      float d = (l < len) ? (pv[l+1]-pv[l]) : 0.f;
      ps[l][c] = run; ds[l][c] = d; run += d;
    }
    frow[c] = pv[0];      // start_pos
    frow[96+c] = run;     // s1 (sum of dseg)
  }
  __syncthreads();
  for (int k = tid; k < NPAIR; k += 256){
    int pr = pairs[k];
    int i = pr >> 7, j = pr & 127;
    float q = 0.f;
    #pragma unroll
    for (int l=0;l<6;l++) q += ps[l][i]*ds[l][j] - ps[l][j]*ds[l][i];
    frow[192+k] = 0.5f*q;
  }
}

// ---------------- fp32 GEMM: xw[row][g] = feat . W_ih[g] + (b_ih+b_hh) ------
__global__ __launch_bounds__(256) void kGemm(const float* feat, const float* wih,
                                             const float* bih, const float* bhh,
                                             float* xw, int row0, int nrows){
  __shared__ __align__(16) float As[16][68];
  __shared__ __align__(16) float Bs[16][68];
  int tid = threadIdx.x;
  int rowBase = blockIdx.x * 64;
  int colBase = blockIdx.y * 64;
  int tx = tid % 16, ty = tid / 16;
  float acc[4][4] = {};
  int lr = tid / 4;            // 0..63
  int lk = (tid % 4) * 4;      // 0,4,8,12
  bool rowOk = (rowBase + lr) < nrows;
  const float* fbase = feat + (size_t)(rowBase+lr)*KF + lk;
  const float* wbase = wih  + (size_t)(colBase+lr)*KF + lk;
  for (int k0 = 0; k0 < KF; k0 += 16){
    float4 a = rowOk ? *(const float4*)(fbase + k0) : make_float4(0.f,0.f,0.f,0.f);
    float4 w = *(const float4*)(wbase + k0);
    As[lk+0][lr]=a.x; As[lk+1][lr]=a.y; As[lk+2][lr]=a.z; As[lk+3][lr]=a.w;
    Bs[lk+0][lr]=w.x; Bs[lk+1][lr]=w.y; Bs[lk+2][lr]=w.z; Bs[lk+3][lr]=w.w;
    __syncthreads();
    #pragma unroll
    for (int kk=0; kk<16; kk++){
      float4 av = *(const float4*)&As[kk][ty*4];
      float4 bv = *(const float4*)&Bs[kk][tx*4];
      float aa[4] = {av.x,av.y,av.z,av.w};
      float bb[4] = {bv.x,bv.y,bv.z,bv.w};
      #pragma unroll
      for (int i2=0;i2<4;i2++)
        #pragma unroll
        for (int j2=0;j2<4;j2++) acc[i2][j2] += aa[i2]*bb[j2];
    }
    __syncthreads();
  }
  #pragma unroll
  for (int i2=0;i2<4;i2++){
    int r = rowBase + ty*4 + i2;
    if (r < nrows){
      #pragma unroll
      for (int j2=0;j2<4;j2++){
        int cg = colBase + tx*4 + j2;
        xw[(size_t)(row0 + r)*G4 + cg] = acc[i2][j2] + bih[cg] + bhh[cg];
      }
    }
  }
}

// ---------------- LSTM: 200 independent recurrences, W_hh in registers -----
__global__ __launch_bounds__(384) void kLstm(const float* xw, const float* whh, float* hsum){
  int b = blockIdx.x;
  int g = threadIdx.x;           // 0..383 (one gate row each)
  __shared__ __align__(16) float h_s[96];
  __shared__ float gbuf[384];
  float wreg[96];
  #pragma unroll
  for (int k=0;k<96;k++) wreg[k] = whh[(size_t)g*96 + k];
  float cval = 0.f, hacc = 0.f;
  if (g < 96) h_s[g] = 0.f;
  __syncthreads();
  const float* xrow = xw + (size_t)b*50*G4;
  for (int t=0;t<50;t++){
    float acc = xrow[t*G4 + g];
    #pragma unroll
    for (int k=0;k<96;k+=4){
      float4 h4 = *(const float4*)&h_s[k];
      acc += wreg[k]*h4.x + wreg[k+1]*h4.y + wreg[k+2]*h4.z + wreg[k+3]*h4.w;
    }
    gbuf[g] = acc;
    __syncthreads();
    if (g < 96){
      float ig = gbuf[g], fg = gbuf[96+g], gg = gbuf[192+g], og = gbuf[288+g];
      float si = 1.f/(1.f+expf(-ig));
      float sf = 1.f/(1.f+expf(-fg));
      float so = 1.f/(1.f+expf(-og));
      cval = sf*cval + si*tanhf(gg);
      float h = so * tanhf(cval);
      h_s[g] = h;
      hacc += h;
    }
    __syncthreads();
  }
  if (g < 96) hsum[(size_t)b*96 + g] = hacc;
}

// ---------------- head: pool over (m, v, s) then FC -------------------------
__global__ void kOut(const float* hsum, const float* wfc, const float* bfc, float* out){
  int n = blockIdx.x;
  __shared__ float pool[96];
  int tid = threadIdx.x;   // 128
  if (tid < 96){
    float a = 0.f;
    for (int mv=0; mv<50; mv++) a += hsum[((size_t)(n*50 + mv))*96 + tid];
    pool[tid] = a / 2500.f;
  }
  __syncthreads();
  if (tid < 60){
    float a = bfc[tid];
    for (int o=0;o<96;o++) a += pool[o]*wfc[tid*96+o];
    out[n*60+tid] = a;
  }
}

extern "C" void kernel_launch(void* const* d_in, const int* in_sizes, int n_in,
                              void* d_out, int out_size, void* d_ws, size_t ws_size,
                              hipStream_t stream){
  const float* x     = (const float*)d_in[0];
  const float* bn_g  = (const float*)d_in[1];
  const float* bn_b  = (const float*)d_in[2];
  const float* bn_m  = (const float*)d_in[3];
  const float* bn_v  = (const float*)d_in[4];
  const float* Ap    = (const float*)d_in[5];
  const float* Ar    = (const float*)d_in[6];
  const float* Wg    = (const float*)d_in[7];
  const float* bg    = (const float*)d_in[8];
  const float* bn2_g = (const float*)d_in[9];
  const float* bn2_b = (const float*)d_in[10];
  const float* bn2_m = (const float*)d_in[11];
  const float* bn2_v = (const float*)d_in[12];
  const float* wih   = (const float*)d_in[13];
  const float* whh   = (const float*)d_in[14];
  const float* bih   = (const float*)d_in[15];
  const float* bhh   = (const float*)d_in[16];
  const float* wfc   = (const float*)d_in[17];
  const float* bfc   = (const float*)d_in[18];
  float* out = (float*)d_out;

  float* ws   = (float*)d_ws;
  float* geff = ws;                       // 360000
  float* beff = geff + 360000;            // 4800
  int*   pairs= (int*)(beff + 4800);      // 4560
  float* pbuf = beff + 4800 + 4560;       // 5,760,000  (200*300*96)
  float* xw   = pbuf + 5760000;           // 3,840,000  (200*50*384)
  float* hsum = xw + 3840000;             // 19,200
  float* feat = hsum + 19200;             // chunk * 4752

  size_t fixedf = 360000u + 4800u + 4560u + 5760000u + 3840000u + 19200u;
  long long availf = (long long)(ws_size/4) - (long long)fixedf;
  int chunk = 64;
  if (availf > 0){
    long long c = availf / KF;
    if (c > 10000) c = 10000;
    chunk = (int)c;
  }
  chunk &= ~63;                 // multiple of 64 for GEMM tiling
  if (chunk < 64) chunk = 64;

  kGeff<<<(2*96*25*75 + 255)/256, 256, 0, stream>>>(bn_g, bn_v, Ap, Ar, Wg, bn2_g, bn2_v, geff);
  kBeff<<<(2*96*25 + 255)/256, 256, 0, stream>>>(bn_g, bn_b, bn_m, bn_v, Ap, Ar, Wg, bg,
                                                 bn2_g, bn2_b, bn2_m, bn2_v, beff);
  kPairs<<<(NPAIR + 255)/256, 256, 0, stream>>>(pairs);
  kP<<<dim3(30, 8), 256, 0, stream>>>(x, geff, beff, pbuf);

  for (int r0 = 0; r0 < 10000; r0 += chunk){
    int nr = 10000 - r0; if (nr > chunk) nr = chunk;
    kFeat<<<nr, 256, 0, stream>>>(pbuf, pairs, feat, r0);
    kGemm<<<dim3((nr + 63)/64, G4/64), 256, 0, stream>>>(feat, wih, bih, bhh, xw, r0, nr);
  }

  kLstm<<<200, 384, 0, stream>>>(xw, whh, hsum);
  kOut<<<4, 128, 0, stream>>>(hsum, wfc, bfc, out);
}

// Round 3
// 1292.542 us; speedup vs baseline: 1.0017x; 1.0017x over previous
//
#include <hip/hip_runtime.h>
#include <math.h>

#define KF 4752          // feature dim: 96 + 96 + 4560
#define G4 384           // 4*C1 gates
#define NPAIR 4560
#define EPSBN 1e-5f

// Segment geometry for T=300, N_SEG=50 (derived exactly, incl. banker's
// rounding of linspace at i=25: 150.5 -> 150).
__device__ __forceinline__ int seg_start(int s){ return (s<=24)? 6*s : 149 + 6*(s-25); }
__device__ __forceinline__ int seg_len(int s){ return (s==24)?5:6; }

// ---------------- precompute: Geff[m][o][v][c*25+u], Beff[m][o][v], pairs ----
__global__ void kGeff(const float* bn_g, const float* bn_v,
                      const float* Ap, const float* Ar, const float* Wg,
                      const float* bn2_g, const float* bn2_v, float* geff){
  int idx = blockIdx.x*256 + threadIdx.x;
  if (idx >= 2*96*25*75) return;
  int cu = idx % 75; int rest = idx/75;
  int v = rest % 25; rest /= 25;
  int o = rest % 96; int m = rest / 96;
  int c = cu/25, u = cu%25;
  int ch = (m*25+u)*3 + c;
  float s1 = bn_g[ch] / sqrtf(bn_v[ch] + EPSBN);
  float s2 = bn2_g[o] / sqrtf(bn2_v[o] + EPSBN);
  float acc = 0.f;
  for (int k=0;k<13;k++){
    float a = Ap[(k*25+v)*25+u] + Ar[(k*25+v)*25+u];
    acc += Wg[o*39 + k*3 + c] * a;
  }
  geff[idx] = acc * s1 * s2;
}

__global__ void kBeff(const float* bn_g,const float* bn_b,const float* bn_m,const float* bn_v,
                      const float* Ap,const float* Ar,const float* Wg,const float* bg,
                      const float* bn2_g,const float* bn2_b,const float* bn2_m,const float* bn2_v,
                      float* beff){
  int idx = blockIdx.x*256+threadIdx.x;
  if (idx >= 2*96*25) return;
  int v = idx%25; int rest = idx/25; int o = rest%96; int m = rest/96;
  float acc = 0.f;
  for (int k=0;k<13;k++) for(int c=0;c<3;c++){
    float w = Wg[o*39+k*3+c];
    for (int u=0;u<25;u++){
      int ch = (m*25+u)*3+c;
      float s1 = bn_g[ch]/sqrtf(bn_v[ch]+EPSBN);
      float t1 = bn_b[ch] - bn_m[ch]*s1;
      acc += w * (Ap[(k*25+v)*25+u]+Ar[(k*25+v)*25+u]) * t1;
    }
  }
  acc += bg[o];
  float s2 = bn2_g[o]/sqrtf(bn2_v[o]+EPSBN);
  beff[idx] = s2*(acc - bn2_m[o]) + bn2_b[o];
}

__global__ void kPairs(int* pairs){
  int k = blockIdx.x*256+threadIdx.x;
  if (k >= NPAIR) return;
  int i=0, rem=k;
  while (rem >= 95 - i){ rem -= (95 - i); i++; }
  int j = i + 1 + rem;
  pairs[k] = (i<<7) | j;
}

// ---------------- p[b=nm*25+v][t][o] = relu(sum_cu Geff*x + Beff) -----------
#define TTILE 10
__global__ __launch_bounds__(256) void kP(const float* x, const float* geff, const float* beff, float* p){
  int nm = blockIdx.y;            // 0..7  (n*2+m)
  int t0 = blockIdx.x * TTILE;
  int m  = nm % 2;
  __shared__ float xs[75*TTILE];
  int tid = threadIdx.x;
  for (int li = tid; li < 75*TTILE; li += 256){
    int u = li % 25; int rest = li/25; int tt = rest % TTILE; int c = rest / TTILE;
    xs[(c*25+u)*TTILE + tt] = x[(((size_t)nm*3 + c)*300 + (t0+tt))*25 + u];
  }
  __syncthreads();
  for (int ow = tid; ow < 2400; ow += 256){
    int o = ow % 96, v = ow / 96;
    const float* g = geff + ((size_t)(m*96+o)*25 + v)*75;
    float b = beff[(m*96+o)*25+v];
    float acc[TTILE];
    #pragma unroll
    for (int t=0;t<TTILE;t++) acc[t] = b;
    for (int cu=0; cu<75; cu++){
      float gv = g[cu];
      #pragma unroll
      for (int t=0;t<TTILE;t++) acc[t] += gv * xs[cu*TTILE+t];
    }
    #pragma unroll
    for (int t=0;t<TTILE;t++)
      p[((size_t)(nm*25+v)*300 + t0+t)*96 + o] = fmaxf(acc[t], 0.f);
  }
}

// ---------------- feat rows: [start(96) | s1(96) | ls2(4560)] ---------------
__global__ __launch_bounds__(256) void kFeat(const float* p, const int* pairs, float* feat, int row0){
  int row = row0 + blockIdx.x;
  int b = row / 50, s = row % 50;
  int S = seg_start(s), len = seg_len(s);
  __shared__ float ps[6][96];
  __shared__ float ds[6][96];
  int tid = threadIdx.x;
  float* frow = feat + (size_t)blockIdx.x * KF;
  if (tid < 96){
    int c = tid;
    float pv[7];
    #pragma unroll
    for (int l=0;l<7;l++) pv[l] = p[((size_t)b*300 + S + l)*96 + c];
    float run = 0.f;
    #pragma unroll
    for (int l=0;l<6;l++){
      float d = (l < len) ? (pv[l+1]-pv[l]) : 0.f;
      ps[l][c] = run; ds[l][c] = d; run += d;
    }
    frow[c] = pv[0];      // start_pos
    frow[96+c] = run;     // s1 (sum of dseg)
  }
  __syncthreads();
  for (int k = tid; k < NPAIR; k += 256){
    int pr = pairs[k];
    int i = pr >> 7, j = pr & 127;
    float q = 0.f;
    #pragma unroll
    for (int l=0;l<6;l++) q += ps[l][i]*ds[l][j] - ps[l][j]*ds[l][i];
    frow[192+k] = 0.5f*q;
  }
}

// ---------------- fp32 GEMM: xw[row][g] = feat . W_ih[g] + (b_ih+b_hh) ------
__global__ __launch_bounds__(256) void kGemm(const float* feat, const float* wih,
                                             const float* bih, const float* bhh,
                                             float* xw, int row0, int nrows){
  __shared__ __align__(16) float As[16][68];
  __shared__ __align__(16) float Bs[16][68];
  int tid = threadIdx.x;
  int rowBase = blockIdx.x * 64;
  int colBase = blockIdx.y * 64;
  int tx = tid % 16, ty = tid / 16;
  float acc[4][4] = {};
  int lr = tid / 4;            // 0..63
  int lk = (tid % 4) * 4;      // 0,4,8,12
  bool rowOk = (rowBase + lr) < nrows;
  const float* fbase = feat + (size_t)(rowBase+lr)*KF + lk;
  const float* wbase = wih  + (size_t)(colBase+lr)*KF + lk;
  for (int k0 = 0; k0 < KF; k0 += 16){
    float4 a = rowOk ? *(const float4*)(fbase + k0) : make_float4(0.f,0.f,0.f,0.f);
    float4 w = *(const float4*)(wbase + k0);
    As[lk+0][lr]=a.x; As[lk+1][lr]=a.y; As[lk+2][lr]=a.z; As[lk+3][lr]=a.w;
    Bs[lk+0][lr]=w.x; Bs[lk+1][lr]=w.y; Bs[lk+2][lr]=w.z; Bs[lk+3][lr]=w.w;
    __syncthreads();
    #pragma unroll
    for (int kk=0; kk<16; kk++){
      float4 av = *(const float4*)&As[kk][ty*4];
      float4 bv = *(const float4*)&Bs[kk][tx*4];
      float aa[4] = {av.x,av.y,av.z,av.w};
      float bb[4] = {bv.x,bv.y,bv.z,bv.w};
      #pragma unroll
      for (int i2=0;i2<4;i2++)
        #pragma unroll
        for (int j2=0;j2<4;j2++) acc[i2][j2] += aa[i2]*bb[j2];
    }
    __syncthreads();
  }
  #pragma unroll
  for (int i2=0;i2<4;i2++){
    int r = rowBase + ty*4 + i2;
    if (r < nrows){
      #pragma unroll
      for (int j2=0;j2<4;j2++){
        int cg = colBase + tx*4 + j2;
        xw[(size_t)(row0 + r)*G4 + cg] = acc[i2][j2] + bih[cg] + bhh[cg];
      }
    }
  }
}

// ---------------- LSTM: 200 independent recurrences, W_hh in registers -----
__global__ __launch_bounds__(384) void kLstm(const float* xw, const float* whh, float* hsum){
  int b = blockIdx.x;
  int g = threadIdx.x;           // 0..383 (one gate row each)
  __shared__ __align__(16) float h_s[96];
  __shared__ float gbuf[384];
  float wreg[96];
  #pragma unroll
  for (int k=0;k<96;k++) wreg[k] = whh[(size_t)g*96 + k];
  float cval = 0.f, hacc = 0.f;
  if (g < 96) h_s[g] = 0.f;
  __syncthreads();
  const float* xrow = xw + (size_t)b*50*G4;
  for (int t=0;t<50;t++){
    float acc = xrow[t*G4 + g];
    #pragma unroll
    for (int k=0;k<96;k+=4){
      float4 h4 = *(const float4*)&h_s[k];
      acc += wreg[k]*h4.x + wreg[k+1]*h4.y + wreg[k+2]*h4.z + wreg[k+3]*h4.w;
    }
    gbuf[g] = acc;
    __syncthreads();
    if (g < 96){
      float ig = gbuf[g], fg = gbuf[96+g], gg = gbuf[192+g], og = gbuf[288+g];
      float si = 1.f/(1.f+expf(-ig));
      float sf = 1.f/(1.f+expf(-fg));
      float so = 1.f/(1.f+expf(-og));
      cval = sf*cval + si*tanhf(gg);
      float h = so * tanhf(cval);
      h_s[g] = h;
      hacc += h;
    }
    __syncthreads();
  }
  if (g < 96) hsum[(size_t)b*96 + g] = hacc;
}

// ---------------- head: pool over (m, v, s) then FC -------------------------
__global__ void kOut(const float* hsum, const float* wfc, const float* bfc, float* out){
  int n = blockIdx.x;
  __shared__ float pool[96];
  int tid = threadIdx.x;   // 128
  if (tid < 96){
    float a = 0.f;
    for (int mv=0; mv<50; mv++) a += hsum[((size_t)(n*50 + mv))*96 + tid];
    pool[tid] = a / 2500.f;
  }
  __syncthreads();
  if (tid < 60){
    float a = bfc[tid];
    for (int o=0;o<96;o++) a += pool[o]*wfc[tid*96+o];
    out[n*60+tid] = a;
  }
}

extern "C" void kernel_launch(void* const* d_in, const int* in_sizes, int n_in,
                              void* d_out, int out_size, void* d_ws, size_t ws_size,
                              hipStream_t stream){
  const float* x     = (const float*)d_in[0];
  const float* bn_g  = (const float*)d_in[1];
  const float* bn_b  = (const float*)d_in[2];
  const float* bn_m  = (const float*)d_in[3];
  const float* bn_v  = (const float*)d_in[4];
  const float* Ap    = (const float*)d_in[5];
  const float* Ar    = (const float*)d_in[6];
  const float* Wg    = (const float*)d_in[7];
  const float* bg    = (const float*)d_in[8];
  const float* bn2_g = (const float*)d_in[9];
  const float* bn2_b = (const float*)d_in[10];
  const float* bn2_m = (const float*)d_in[11];
  const float* bn2_v = (const float*)d_in[12];
  const float* wih   = (const float*)d_in[13];
  const float* whh   = (const float*)d_in[14];
  const float* bih   = (const float*)d_in[15];
  const float* bhh   = (const float*)d_in[16];
  const float* wfc   = (const float*)d_in[17];
  const float* bfc   = (const float*)d_in[18];
  float* out = (float*)d_out;

  float* ws   = (float*)d_ws;
  float* geff = ws;                       // 360000
  float* beff = geff + 360000;            // 4800
  int*   pairs= (int*)(beff + 4800);      // 4560
  float* pbuf = beff + 4800 + 4560;       // 5,760,000  (200*300*96)
  float* xw   = pbuf + 5760000;           // 3,840,000  (200*50*384)
  float* hsum = xw + 3840000;             // 19,200
  float* feat = hsum + 19200;             // chunk * 4752

  size_t fixedf = 360000u + 4800u + 4560u + 5760000u + 3840000u + 19200u;
  long long availf = (long long)(ws_size/4) - (long long)fixedf;
  int chunk = 64;
  if (availf > 0){
    long long c = availf / KF;
    if (c > 10000) c = 10000;
    chunk = (int)c;
  }
  chunk &= ~63;                 // multiple of 64 for GEMM tiling
  if (chunk < 64) chunk = 64;

  kGeff<<<(2*96*25*75 + 255)/256, 256, 0, stream>>>(bn_g, bn_v, Ap, Ar, Wg, bn2_g, bn2_v, geff);
  kBeff<<<(2*96*25 + 255)/256, 256, 0, stream>>>(bn_g, bn_b, bn_m, bn_v, Ap, Ar, Wg, bg,
                                                 bn2_g, bn2_b, bn2_m, bn2_v, beff);
  kPairs<<<(NPAIR + 255)/256, 256, 0, stream>>>(pairs);
  kP<<<dim3(30, 8), 256, 0, stream>>>(x, geff, beff, pbuf);

  for (int r0 = 0; r0 < 10000; r0 += chunk){
    int nr = 10000 - r0; if (nr > chunk) nr = chunk;
    kFeat<<<nr, 256, 0, stream>>>(pbuf, pairs, feat, r0);
    kGemm<<<dim3((nr + 63)/64, G4/64), 256, 0, stream>>>(feat, wih, bih, bhh, xw, r0, nr);
  }

  kLstm<<<200, 384, 0, stream>>>(xw, whh, hsum);
  kOut<<<4, 128, 0, stream>>>(hsum, wfc, bfc, out);
}